// Round 2
// baseline (248.154 us; speedup 1.0000x reference)
//
#include <hip/hip_runtime.h>
#include <hip/hip_bf16.h>

#define NN 8192
#define CC 256
#define CQK 32
#define JS 2   // pass1 j-splits

using bf16x8 = __attribute__((ext_vector_type(8))) short;
using s16x4  = __attribute__((ext_vector_type(4))) short;
using f32x4  = __attribute__((ext_vector_type(4))) float;

static __device__ __forceinline__ unsigned short f2bf(float x) {
    union { __hip_bfloat16 h; unsigned short u; } cv;
    cv.h = __float2bfloat16(x);
    return cv.u;
}
static __device__ __forceinline__ float bf2f(unsigned short u) {
    union { unsigned short u; __hip_bfloat16 h; } cv;
    cv.u = u;
    return __bfloat162float(cv.h);
}
static __device__ __forceinline__ float fexp2(float x) { return __builtin_amdgcn_exp2f(x); }

// ---------------------------------------------------------------------------
// Kernel 1: projections. q = (f @ Wqk^T) * sqrt(log2 e), stored hi/lo bf16.
//           v = f @ Wv^T + bv, stored transposed vT[c][n] bf16.
// grid 1024 x 256 thr; 8 rows of f per block.
// ---------------------------------------------------------------------------
__global__ __launch_bounds__(256) void proj_kernel(
    const float* __restrict__ f, const float* __restrict__ Wqk,
    const float* __restrict__ Wv, const float* __restrict__ bv,
    unsigned short* __restrict__ qhi, unsigned short* __restrict__ qlo,
    unsigned short* __restrict__ vT)
{
    __shared__ __align__(16) float fl[8][CC];
    const int t  = threadIdx.x;
    const int r0 = blockIdx.x * 8;

    {
        const float4* src = (const float4*)(f + (size_t)r0 * CC);
        float4* dst = (float4*)&fl[0][0];
        dst[t]       = src[t];
        dst[t + 256] = src[t + 256];
    }
    __syncthreads();

    {   // v column c = t for 8 rows
        float acc[8];
#pragma unroll
        for (int r = 0; r < 8; ++r) acc[r] = 0.f;
        const float4* w4 = (const float4*)(Wv + (size_t)t * CC);
        for (int k4 = 0; k4 < 64; ++k4) {
            float4 wv = w4[k4];
#pragma unroll
            for (int r = 0; r < 8; ++r) {
                const float4 fv = *(const float4*)&fl[r][k4 * 4];
                acc[r] = fmaf(wv.x, fv.x, acc[r]);
                acc[r] = fmaf(wv.y, fv.y, acc[r]);
                acc[r] = fmaf(wv.z, fv.z, acc[r]);
                acc[r] = fmaf(wv.w, fv.w, acc[r]);
            }
        }
        float b = bv[t];
#pragma unroll
        for (int r = 0; r < 8; ++r)
            vT[(size_t)t * NN + (r0 + r)] = f2bf(acc[r] + b);
    }

    {   // q: thread t -> col cq = t&31, row rg = t>>5 (0..7)
        const int cq = t & 31;
        const int rg = t >> 5;
        const float4* w4 = (const float4*)(Wqk + (size_t)cq * CC);
        float a = 0.f;
        for (int k4 = 0; k4 < 64; ++k4) {
            float4 wq = w4[k4];
            const float4 fv = *(const float4*)&fl[rg][k4 * 4];
            a = fmaf(wq.x, fv.x, a);
            a = fmaf(wq.y, fv.y, a);
            a = fmaf(wq.z, fv.z, a);
            a = fmaf(wq.w, fv.w, a);
        }
        a *= 1.2011224087864498f;          // sqrt(log2 e): energies in exp2-domain
        unsigned short h = f2bf(a);
        unsigned short l = f2bf(a - bf2f(h));
        qhi[(size_t)(r0 + rg) * CQK + cq] = h;
        qlo[(size_t)(r0 + rg) * CQK + cq] = l;
    }
}

// ---------------------------------------------------------------------------
// Kernel 2: per-i-row partial softmax stats over a j-range.
// E via hi/lo bf16 MFMA; D: row=j (4*lc+r), col=i (lane&15) -> each lane's
// 4 regs share one i-row => block-of-4 online update (5 exp2 / 4 vals).
// grid (NN/32)*JS x 512 thr.
// ---------------------------------------------------------------------------
__global__ __launch_bounds__(512, 4) void pass1_kernel(
    const unsigned short* __restrict__ qhi,
    const unsigned short* __restrict__ qlo,
    float* __restrict__ pm, float* __restrict__ ps)
{
    const int t    = threadIdx.x;
    const int lane = t & 63;
    const int w    = t >> 6;
    const int lr   = lane & 15;
    const int lc   = lane >> 4;
    const int ig   = blockIdx.x & 255;
    const int js   = blockIdx.x >> 8;
    const int i0   = ig * 32;
    const int NJ   = NN / JS;
    const int jb   = js * NJ;

    bf16x8 bihi[2], bilo[2];   // B = q_i (fixed): 2 tiles of 16 i-cols
#pragma unroll
    for (int f_ = 0; f_ < 2; ++f_) {
        int row = i0 + 16 * f_ + lr;
        bihi[f_] = *(const bf16x8*)(qhi + (size_t)row * CQK + 8 * lc);
        bilo[f_] = *(const bf16x8*)(qlo + (size_t)row * CQK + 8 * lc);
    }

    float m_run[2] = { -INFINITY, -INFINITY };
    float s_run[2] = { 0.f, 0.f };

    int jr = jb + 16 * w + lr;
    bf16x8 ajhi = *(const bf16x8*)(qhi + (size_t)jr * CQK + 8 * lc);
    bf16x8 ajlo = *(const bf16x8*)(qlo + (size_t)jr * CQK + 8 * lc);

    for (int jstep = 0; jstep < NJ; jstep += 128) {
        int nxt = (jstep + 128 < NJ) ? jstep + 128 : jstep;
        int jn = jb + nxt + 16 * w + lr;
        bf16x8 nahi = *(const bf16x8*)(qhi + (size_t)jn * CQK + 8 * lc);
        bf16x8 nalo = *(const bf16x8*)(qlo + (size_t)jn * CQK + 8 * lc);
#pragma unroll
        for (int f_ = 0; f_ < 2; ++f_) {
            f32x4 e = {0.f, 0.f, 0.f, 0.f};
            e = __builtin_amdgcn_mfma_f32_16x16x32_bf16(ajlo, bihi[f_], e, 0, 0, 0);
            e = __builtin_amdgcn_mfma_f32_16x16x32_bf16(ajhi, bilo[f_], e, 0, 0, 0);
            e = __builtin_amdgcn_mfma_f32_16x16x32_bf16(ajhi, bihi[f_], e, 0, 0, 0);
            float ml = fmaxf(fmaxf(e[0], e[1]), fmaxf(e[2], e[3]));
            float mo = m_run[f_];
            float mn = fmaxf(mo, ml);
            float cr = fexp2(mo - mn);          // 1 when mn==mo; 0 on first iter
            s_run[f_] = fmaf(s_run[f_], cr,
                             fexp2(e[0] - mn) + fexp2(e[1] - mn) +
                             fexp2(e[2] - mn) + fexp2(e[3] - mn));
            m_run[f_] = mn;
        }
        ajhi = nahi; ajlo = nalo;
    }

    // lanes with equal (lane&15) share the i-col: butterfly over bits 4,5
#pragma unroll
    for (int off = 16; off < 64; off <<= 1) {
#pragma unroll
        for (int f_ = 0; f_ < 2; ++f_) {
            float mo = __shfl_xor(m_run[f_], off);
            float so = __shfl_xor(s_run[f_], off);
            float mn = fmaxf(m_run[f_], mo);
            s_run[f_] = s_run[f_] * fexp2(m_run[f_] - mn) + so * fexp2(mo - mn);
            m_run[f_] = mn;
        }
    }

    __shared__ float red_m[8][32];
    __shared__ float red_s[8][32];
    if (lane < 16) {
        red_m[w][lr]      = m_run[0];
        red_m[w][16 + lr] = m_run[1];
        red_s[w][lr]      = s_run[0];
        red_s[w][16 + lr] = s_run[1];
    }
    __syncthreads();
    if (t < 32) {
        float m = red_m[0][t], s = red_s[0][t];
#pragma unroll
        for (int ww = 1; ww < 8; ++ww) {
            float m2 = red_m[ww][t], s2 = red_s[ww][t];
            float mn = fmaxf(m, m2);
            s = s * fexp2(m - mn) + s2 * fexp2(m2 - mn);
            m = mn;
        }
        pm[(size_t)js * NN + i0 + t] = m;
        ps[(size_t)js * NN + i0 + t] = s;
    }
}

// ---------------------------------------------------------------------------
// Kernel 2b: merge j-split partials; bias[i] = m_i + log2(s_i).
// ---------------------------------------------------------------------------
__global__ __launch_bounds__(256) void finalize_kernel(
    const float* __restrict__ pm, const float* __restrict__ ps,
    float* __restrict__ bias)
{
    int i = blockIdx.x * 256 + threadIdx.x;
    float m = pm[i], s = ps[i];
#pragma unroll
    for (int k = 1; k < JS; ++k) {
        float m2 = pm[(size_t)k * NN + i], s2 = ps[(size_t)k * NN + i];
        float mn = fmaxf(m, m2);
        s = s * fexp2(m - mn) + s2 * fexp2(m2 - mn);
        m = mn;
    }
    bias[i] = m + __builtin_amdgcn_logf(s);
}

// ---------------------------------------------------------------------------
// Kernel 3: partial[isp][j,c] = sum_{i in split} exp2(e_ij - bias_i) * v[i,c]
// grid 256*SPLIT x 512 thr. Per block: 32 j x 256 c, i-step 64.
// Wave w: E-tile (i-window 16*(w&3), j-half w>>2); PV cols c in [32w, 32w+32).
// E computed as mfma(q_i, q_j): lane's 4 regs = 4 consecutive i at one j
// -> single b64 P write; P dbuf in LDS -> ONE barrier per step.
// ---------------------------------------------------------------------------
template<int SPLIT, bool DIRECT>
__global__ __launch_bounds__(512, 4) void pass2_kernel(
    const unsigned short* __restrict__ qhi,
    const unsigned short* __restrict__ qlo,
    const unsigned short* __restrict__ vT,
    const float* __restrict__ bias,
    const float* __restrict__ f,
    const float* __restrict__ gp,
    float* __restrict__ dst)
{
    __shared__ __align__(16) unsigned short p_lds[2][32][72];
    const int t    = threadIdx.x;
    const int lane = t & 63;
    const int w    = t >> 6;
    const int lr   = lane & 15;
    const int lc   = lane >> 4;
    const int jb   = (blockIdx.x & 255) * 32;
    const int isp  = blockIdx.x >> 8;
    const int IL   = NN / SPLIT;
    const int ibase = isp * IL;
    const int jf   = w >> 2;          // j-half for E
    const int iw   = 16 * (w & 3);    // i-window within 64-step

    bf16x8 qjhi, qjlo;                // B = q_j (fixed per wave)
    {
        int row = jb + 16 * jf + lr;
        qjhi = *(const bf16x8*)(qhi + (size_t)row * CQK + 8 * lc);
        qjlo = *(const bf16x8*)(qlo + (size_t)row * CQK + 8 * lc);
    }
    bf16x8 qihi, qilo;                // A = q_i (advances per step)
    {
        int row = ibase + iw + lr;
        qihi = *(const bf16x8*)(qhi + (size_t)row * CQK + 8 * lc);
        qilo = *(const bf16x8*)(qlo + (size_t)row * CQK + 8 * lc);
    }
    f32x4 b4 = *(const f32x4*)(bias + ibase + iw + 4 * lc);

    f32x4 acc[2][2];
    {
        f32x4 z = {0.f, 0.f, 0.f, 0.f};
        acc[0][0] = z; acc[0][1] = z; acc[1][0] = z; acc[1][1] = z;
    }

    for (int i0s = 0; i0s < IL; i0s += 64) {
        const int ig0 = ibase + i0s;
        // V fragments for this step (issue early; L2/L3-resident)
        bf16x8 bv8[2][2];
#pragma unroll
        for (int ks = 0; ks < 2; ++ks)
#pragma unroll
            for (int cf = 0; cf < 2; ++cf)
                bv8[ks][cf] = *(const bf16x8*)(
                    vT + (size_t)(32 * w + 16 * cf + lr) * NN + ig0 + 32 * ks + 8 * lc);

        // prefetch next-step A fragments + bias
        int nxt = (i0s + 64 < IL) ? i0s + 64 : i0s;
        bf16x8 nihi = *(const bf16x8*)(qhi + (size_t)(ibase + nxt + iw + lr) * CQK + 8 * lc);
        bf16x8 nilo = *(const bf16x8*)(qlo + (size_t)(ibase + nxt + iw + lr) * CQK + 8 * lc);
        f32x4  nb4  = *(const f32x4*)(bias + ibase + nxt + iw + 4 * lc);

        // E tile: e[i, j], hi/lo split, fp32 accum
        f32x4 ee = {0.f, 0.f, 0.f, 0.f};
        ee = __builtin_amdgcn_mfma_f32_16x16x32_bf16(qilo, qjhi, ee, 0, 0, 0);
        ee = __builtin_amdgcn_mfma_f32_16x16x32_bf16(qihi, qjlo, ee, 0, 0, 0);
        ee = __builtin_amdgcn_mfma_f32_16x16x32_bf16(qihi, qjhi, ee, 0, 0, 0);

        // p = exp2(e - bias_i); 4 consecutive i at one j -> packed b64 write
        s16x4 pk;
#pragma unroll
        for (int r = 0; r < 4; ++r)
            pk[r] = (short)f2bf(fexp2(ee[r] - b4[r]));
        const int buf = (i0s >> 6) & 1;
        *(s16x4*)&p_lds[buf][16 * jf + lr][iw + 4 * lc] = pk;

        __syncthreads();   // p[buf] complete; prev-step reads were pre-barrier

#pragma unroll
        for (int ks = 0; ks < 2; ++ks) {
            bf16x8 pa0 = *(const bf16x8*)&p_lds[buf][lr][32 * ks + 8 * lc];
            bf16x8 pa1 = *(const bf16x8*)&p_lds[buf][16 + lr][32 * ks + 8 * lc];
#pragma unroll
            for (int cf = 0; cf < 2; ++cf) {
                acc[0][cf] = __builtin_amdgcn_mfma_f32_16x16x32_bf16(pa0, bv8[ks][cf], acc[0][cf], 0, 0, 0);
                acc[1][cf] = __builtin_amdgcn_mfma_f32_16x16x32_bf16(pa1, bv8[ks][cf], acc[1][cf], 0, 0, 0);
            }
        }
        qihi = nihi; qilo = nilo; b4 = nb4;
    }

    if (DIRECT) {
        float g = gp[0];
#pragma unroll
        for (int jp = 0; jp < 2; ++jp)
#pragma unroll
            for (int cf = 0; cf < 2; ++cf)
#pragma unroll
                for (int r = 0; r < 4; ++r) {
                    int j = jb + 16 * jp + 4 * lc + r;
                    int c = 32 * w + 16 * cf + lr;
                    dst[(size_t)j * CC + c] = fmaf(g, acc[jp][cf][r], f[(size_t)j * CC + c]);
                }
    } else {
        float* part = dst + (size_t)isp * NN * CC;
#pragma unroll
        for (int jp = 0; jp < 2; ++jp)
#pragma unroll
            for (int cf = 0; cf < 2; ++cf)
#pragma unroll
                for (int r = 0; r < 4; ++r) {
                    int j = jb + 16 * jp + 4 * lc + r;
                    int c = 32 * w + 16 * cf + lr;
                    part[(size_t)j * CC + c] = acc[jp][cf][r];
                }
    }
}

// ---------------------------------------------------------------------------
// Kernel 4: out = gamma * sum_splits(part) + f
// ---------------------------------------------------------------------------
template<int SPLIT>
__global__ __launch_bounds__(256) void reduce_kernel(
    const float* __restrict__ part, const float* __restrict__ f,
    const float* __restrict__ gp, float* __restrict__ out)
{
    size_t idx = (size_t)blockIdx.x * 256 + threadIdx.x;   // f32x4 units
    const f32x4* p4 = (const f32x4*)part;
    f32x4 s = p4[idx];
#pragma unroll
    for (int k = 1; k < SPLIT; ++k) s += p4[(size_t)k * (NN * CC / 4) + idx];
    f32x4 fv = ((const f32x4*)f)[idx];
    float g = gp[0];
    f32x4 o;
#pragma unroll
    for (int r = 0; r < 4; ++r) o[r] = fmaf(g, s[r], fv[r]);
    ((f32x4*)out)[idx] = o;
}

// ---------------------------------------------------------------------------
extern "C" void kernel_launch(void* const* d_in, const int* in_sizes, int n_in,
                              void* d_out, int out_size, void* d_ws, size_t ws_size,
                              hipStream_t stream) {
    const float* f     = (const float*)d_in[0];
    const float* Wqk   = (const float*)d_in[1];
    const float* Wv    = (const float*)d_in[2];
    const float* bv    = (const float*)d_in[3];
    const float* gamma = (const float*)d_in[4];
    float* out = (float*)d_out;

    char* ws = (char*)d_ws;
    unsigned short* qhi = (unsigned short*)ws;                         // 512 KB
    unsigned short* qlo = (unsigned short*)(ws + (512 << 10));         // 512 KB
    unsigned short* vT  = (unsigned short*)(ws + (1 << 20));           // 4 MB
    float* pm   = (float*)(ws + (5 << 20));                            // 64 KB
    float* ps   = (float*)(ws + (5 << 20) + (64 << 10));               // 64 KB
    float* bias = (float*)(ws + (5 << 20) + (128 << 10));              // 32 KB
    float* part = (float*)(ws + (6 << 20));                            // SPLIT*8 MB

    proj_kernel<<<dim3(NN / 8), dim3(256), 0, stream>>>(f, Wqk, Wv, bv, qhi, qlo, vT);
    pass1_kernel<<<dim3((NN / 32) * JS), dim3(512), 0, stream>>>(qhi, qlo, pm, ps);
    finalize_kernel<<<dim3(NN / 256), dim3(256), 0, stream>>>(pm, ps, bias);

    const size_t PB = (size_t)NN * CC * 4;   // one partial buffer: 8 MB
    const size_t B0 = (size_t)6 << 20;
    if (ws_size >= B0 + 4 * PB) {
        pass2_kernel<4, false><<<dim3(256 * 4), dim3(512), 0, stream>>>(qhi, qlo, vT, bias, f, gamma, part);
        reduce_kernel<4><<<dim3(NN * CC / 1024), dim3(256), 0, stream>>>(part, f, gamma, out);
    } else if (ws_size >= B0 + 2 * PB) {
        pass2_kernel<2, false><<<dim3(256 * 2), dim3(512), 0, stream>>>(qhi, qlo, vT, bias, f, gamma, part);
        reduce_kernel<2><<<dim3(NN * CC / 1024), dim3(256), 0, stream>>>(part, f, gamma, out);
    } else if (ws_size >= B0 + 1 * PB) {
        pass2_kernel<1, false><<<dim3(256), dim3(512), 0, stream>>>(qhi, qlo, vT, bias, f, gamma, part);
        reduce_kernel<1><<<dim3(NN * CC / 1024), dim3(256), 0, stream>>>(part, f, gamma, out);
    } else {
        pass2_kernel<1, true><<<dim3(256), dim3(512), 0, stream>>>(qhi, qlo, vT, bias, f, gamma, out);
    }
}

// Round 3
// 197.900 us; speedup vs baseline: 1.2539x; 1.2539x over previous
//
#include <hip/hip_runtime.h>
#include <hip/hip_bf16.h>

#define NN 8192
#define CC 256
#define CQK 32
#define JS 2   // pass1 j-splits

using bf16x8 = __attribute__((ext_vector_type(8))) short;
using s16x4  = __attribute__((ext_vector_type(4))) short;
using f32x4  = __attribute__((ext_vector_type(4))) float;
using f32x16 = __attribute__((ext_vector_type(16))) float;

static __device__ __forceinline__ unsigned short f2bf(float x) {
    union { __hip_bfloat16 h; unsigned short u; } cv;
    cv.h = __float2bfloat16(x);
    return cv.u;
}
static __device__ __forceinline__ float bf2f(unsigned short u) {
    union { unsigned short u; __hip_bfloat16 h; } cv;
    cv.u = u;
    return __bfloat162float(cv.h);
}
static __device__ __forceinline__ float fexp2(float x) { return __builtin_amdgcn_exp2f(x); }
static __device__ __forceinline__ int packbf(float lo, float hi) {
    return (int)f2bf(lo) | ((int)f2bf(hi) << 16);
}

// ---------------------------------------------------------------------------
// Kernel 1a: q = (f @ Wqk^T) * sqrt(log2 e), stored hi/lo bf16.
// grid 1024 x 256 thr; 8 rows per block; 1 output per thread.
// ---------------------------------------------------------------------------
__global__ __launch_bounds__(256) void proj_q_kernel(
    const float* __restrict__ f, const float* __restrict__ Wqk,
    unsigned short* __restrict__ qhi, unsigned short* __restrict__ qlo)
{
    __shared__ __align__(16) float fl[8][CC];
    const int t  = threadIdx.x;
    const int r0 = blockIdx.x * 8;
    {
        const float4* src = (const float4*)(f + (size_t)r0 * CC);
        float4* dst = (float4*)&fl[0][0];
        dst[t]       = src[t];
        dst[t + 256] = src[t + 256];
    }
    __syncthreads();
    const int cq = t & 31;
    const int rg = t >> 5;
    const float4* w4 = (const float4*)(Wqk + (size_t)cq * CC);
    float a = 0.f;
    for (int k4 = 0; k4 < 64; ++k4) {
        float4 wq = w4[k4];
        const float4 fv = *(const float4*)&fl[rg][k4 * 4];
        a = fmaf(wq.x, fv.x, a);
        a = fmaf(wq.y, fv.y, a);
        a = fmaf(wq.z, fv.z, a);
        a = fmaf(wq.w, fv.w, a);
    }
    a *= 1.2011224087864498f;              // sqrt(log2 e) -> exp2 domain
    unsigned short hh = f2bf(a);
    unsigned short ll = f2bf(a - bf2f(hh));
    qhi[(size_t)(r0 + rg) * CQK + cq] = hh;
    qlo[(size_t)(r0 + rg) * CQK + cq] = ll;
}

// ---------------------------------------------------------------------------
// Kernel 1b: v = f @ Wv^T + bv via single-bf16 32x32x16 MFMA.
// Output layout vB[i>>3][c][i&7] bf16 -> PV B-frags are coalesced b128 loads.
// grid 256 x 256 thr (4 waves); block: 32 n-rows x 256 c; wave: 32 n x 64 c.
// ---------------------------------------------------------------------------
__global__ __launch_bounds__(256, 4) void proj_v_kernel(
    const float* __restrict__ f, const float* __restrict__ Wv,
    const float* __restrict__ bv, unsigned short* __restrict__ vB)
{
    const int t    = threadIdx.x;
    const int lane = t & 63;
    const int w    = t >> 6;
    const int l31  = lane & 31;
    const int h    = lane >> 5;
    const int nb   = blockIdx.x * 32;
    const int cb   = w * 64;

    f32x16 acc[2];
#pragma unroll
    for (int cf = 0; cf < 2; ++cf)
#pragma unroll
        for (int r = 0; r < 16; ++r) acc[cf][r] = 0.f;

    const float* frow = f + (size_t)(nb + l31) * CC;
    for (int ks = 0; ks < 16; ++ks) {
        const int k0 = ks * 16 + 8 * h;
        float4 a0 = *(const float4*)(frow + k0);
        float4 a1 = *(const float4*)(frow + k0 + 4);
        bf16x8 af;
        af[0] = (short)f2bf(a0.x); af[1] = (short)f2bf(a0.y);
        af[2] = (short)f2bf(a0.z); af[3] = (short)f2bf(a0.w);
        af[4] = (short)f2bf(a1.x); af[5] = (short)f2bf(a1.y);
        af[6] = (short)f2bf(a1.z); af[7] = (short)f2bf(a1.w);
#pragma unroll
        for (int cf = 0; cf < 2; ++cf) {
            const float* wrow = Wv + (size_t)(cb + 32 * cf + l31) * CC + k0;
            float4 b0 = *(const float4*)(wrow);
            float4 b1 = *(const float4*)(wrow + 4);
            bf16x8 bw;
            bw[0] = (short)f2bf(b0.x); bw[1] = (short)f2bf(b0.y);
            bw[2] = (short)f2bf(b0.z); bw[3] = (short)f2bf(b0.w);
            bw[4] = (short)f2bf(b1.x); bw[5] = (short)f2bf(b1.y);
            bw[6] = (short)f2bf(b1.z); bw[7] = (short)f2bf(b1.w);
            acc[cf] = __builtin_amdgcn_mfma_f32_32x32x16_bf16(af, bw, acc[cf], 0, 0, 0);
        }
    }
#pragma unroll
    for (int cf = 0; cf < 2; ++cf) {
        const int cg = cb + 32 * cf + l31;
        const float bvc = bv[cg];
#pragma unroll
        for (int rg = 0; rg < 4; ++rg) {
            // rows n = nb + 4h + r + 8rg -> block ib, elems 4h..4h+3
            const int ib = (nb >> 3) + rg;
            s16x4 pk;
#pragma unroll
            for (int r = 0; r < 4; ++r)
                pk[r] = (short)f2bf(acc[cf][4 * rg + r] + bvc);
            *(s16x4*)(vB + ((size_t)ib * CC + cg) * 8 + 4 * h) = pk;
        }
    }
}

// ---------------------------------------------------------------------------
// Kernel 2: per-i partial softmax stats over a j-range, 32x32 E tiles.
// E = mfma(q_j, q_i): D[row=j][col=i]; lane owns col i = lane&31, 16 j-vals.
// grid 512 (256 i-tiles x JS) x 256 thr (4 waves, each 1/4 of j-range).
// ---------------------------------------------------------------------------
__global__ __launch_bounds__(256, 4) void pass1_kernel(
    const unsigned short* __restrict__ qhi,
    const unsigned short* __restrict__ qlo,
    float* __restrict__ pm, float* __restrict__ ps)
{
    const int t    = threadIdx.x;
    const int lane = t & 63;
    const int w    = t >> 6;
    const int l31  = lane & 31;
    const int h    = lane >> 5;
    const int i0   = (blockIdx.x & 255) * 32;
    const int js   = blockIdx.x >> 8;
    const int JCH  = NN / JS / 4;            // 1024 j per wave
    const int jbase = js * (NN / JS) + w * JCH;

    const size_t qir = (size_t)(i0 + l31) * CQK;
    const bf16x8 bih0 = *(const bf16x8*)(qhi + qir + 8 * h);
    const bf16x8 bih1 = *(const bf16x8*)(qhi + qir + 16 + 8 * h);
    const bf16x8 bil0 = *(const bf16x8*)(qlo + qir + 8 * h);
    const bf16x8 bil1 = *(const bf16x8*)(qlo + qir + 16 + 8 * h);

    float m = -INFINITY, s = 0.f;

    for (int st = 0; st < JCH; st += 32) {
        const size_t qjr = (size_t)(jbase + st + l31) * CQK;
        bf16x8 ah0 = *(const bf16x8*)(qhi + qjr + 8 * h);
        bf16x8 ah1 = *(const bf16x8*)(qhi + qjr + 16 + 8 * h);
        bf16x8 al0 = *(const bf16x8*)(qlo + qjr + 8 * h);
        bf16x8 al1 = *(const bf16x8*)(qlo + qjr + 16 + 8 * h);
        f32x16 ee = {0,0,0,0,0,0,0,0,0,0,0,0,0,0,0,0};
        ee = __builtin_amdgcn_mfma_f32_32x32x16_bf16(al0, bih0, ee, 0, 0, 0);
        ee = __builtin_amdgcn_mfma_f32_32x32x16_bf16(al1, bih1, ee, 0, 0, 0);
        ee = __builtin_amdgcn_mfma_f32_32x32x16_bf16(ah0, bil0, ee, 0, 0, 0);
        ee = __builtin_amdgcn_mfma_f32_32x32x16_bf16(ah1, bil1, ee, 0, 0, 0);
        ee = __builtin_amdgcn_mfma_f32_32x32x16_bf16(ah0, bih0, ee, 0, 0, 0);
        ee = __builtin_amdgcn_mfma_f32_32x32x16_bf16(ah1, bih1, ee, 0, 0, 0);
        float tm = ee[0];
#pragma unroll
        for (int r = 1; r < 16; ++r) tm = fmaxf(tm, ee[r]);
        float mn = fmaxf(m, tm);
        float a_ = 0.f;
#pragma unroll
        for (int r = 0; r < 16; ++r) a_ += fexp2(ee[r] - mn);
        s = fmaf(s, fexp2(m - mn), a_);
        m = mn;
    }
    {   // merge the two h-halves (same i-col)
        float mo = __shfl_xor(m, 32);
        float so = __shfl_xor(s, 32);
        float mn = fmaxf(m, mo);
        s = s * fexp2(m - mn) + so * fexp2(mo - mn);
        m = mn;
    }
    __shared__ float rm[4][32];
    __shared__ float rs[4][32];
    if (lane < 32) { rm[w][l31] = m; rs[w][l31] = s; }
    __syncthreads();
    if (t < 32) {
        float mf = rm[0][t], sf = rs[0][t];
#pragma unroll
        for (int ww = 1; ww < 4; ++ww) {
            float m2 = rm[ww][t], s2 = rs[ww][t];
            float mn = fmaxf(mf, m2);
            sf = sf * fexp2(mf - mn) + s2 * fexp2(m2 - mn);
            mf = mn;
        }
        pm[(size_t)js * NN + i0 + t] = mf;
        ps[(size_t)js * NN + i0 + t] = sf;
    }
}

// ---------------------------------------------------------------------------
// Kernel 2b: merge j-split partials; bias[i] = m_i + log2(s_i).
// ---------------------------------------------------------------------------
__global__ __launch_bounds__(256) void finalize_kernel(
    const float* __restrict__ pm, const float* __restrict__ ps,
    float* __restrict__ bias)
{
    int i = blockIdx.x * 256 + threadIdx.x;
    float m = pm[i], s = ps[i];
#pragma unroll
    for (int k = 1; k < JS; ++k) {
        float m2 = pm[(size_t)k * NN + i], s2 = ps[(size_t)k * NN + i];
        float mn = fmaxf(m, m2);
        s = s * fexp2(m - mn) + s2 * fexp2(m2 - mn);
        m = mn;
    }
    bias[i] = m + __builtin_amdgcn_logf(s);   // v_log_f32 = log2
}

// ---------------------------------------------------------------------------
// Kernel 3: barrier-free PV. partial[isp][j,c] = sum_i exp2(e_ij - bias_i)*v[i,c]
// grid 64*ISPLIT x 512 thr (8 waves). Block: 128 j x 256 c. Wave: 32 j x 128 c.
// Per 32-i step: E = mfma(q_i, q_j) 32x32 (6 MFMA) -> exp2 -> pack ->
// shfl_xor(32) redistribution -> 2 PV A-frags -> 8 PV MFMA. No LDS, no barrier.
// ---------------------------------------------------------------------------
template<int ISPLIT, bool DIRECT>
__global__ __launch_bounds__(512, 2) void pass2_kernel(
    const unsigned short* __restrict__ qhi,
    const unsigned short* __restrict__ qlo,
    const unsigned short* __restrict__ vB,
    const float* __restrict__ bias,
    const float* __restrict__ f,
    const float* __restrict__ gp,
    float* __restrict__ dst)
{
    const int t    = threadIdx.x;
    const int lane = t & 63;
    const int w    = t >> 6;
    const int l31  = lane & 31;
    const int h    = lane >> 5;

    int jblk, isp;
    if (ISPLIT == 4) {
        // XCD-aware: isp lives on one XCD pair -> its vB slice stays in L2
        const int xcd  = blockIdx.x & 7;
        const int slot = blockIdx.x >> 3;     // 0..31
        isp  = xcd >> 1;
        jblk = slot * 2 + (xcd & 1);          // 0..63
    } else {
        jblk = blockIdx.x & 63;
        isp  = blockIdx.x >> 6;
    }
    const int jb   = jblk * 128;
    const int jw   = w & 3, cw = w >> 2;
    const int jrow = jb + 32 * jw;
    const int cb   = 128 * cw;
    const int IL   = NN / ISPLIT;
    const int ibase = isp * IL;

    const size_t qjr = (size_t)(jrow + l31) * CQK;
    const bf16x8 bjh0 = *(const bf16x8*)(qhi + qjr + 8 * h);
    const bf16x8 bjh1 = *(const bf16x8*)(qhi + qjr + 16 + 8 * h);
    const bf16x8 bjl0 = *(const bf16x8*)(qlo + qjr + 8 * h);
    const bf16x8 bjl1 = *(const bf16x8*)(qlo + qjr + 16 + 8 * h);

    f32x16 acc[4];
#pragma unroll
    for (int cf = 0; cf < 4; ++cf)
#pragma unroll
        for (int r = 0; r < 16; ++r) acc[cf][r] = 0.f;

    for (int i0s = ibase; i0s < ibase + IL; i0s += 32) {
        // V B-frags: lane (c=l31, h) holds V[i0s+16*s2+8h .. +7][c]
        bf16x8 vf[2][4];
#pragma unroll
        for (int s2 = 0; s2 < 2; ++s2)
#pragma unroll
            for (int cf = 0; cf < 4; ++cf)
                vf[s2][cf] = *(const bf16x8*)(
                    vB + ((size_t)((i0s >> 3) + 2 * s2 + h) * CC + cb + 32 * cf + l31) * 8);

        // q_i A-frags
        const size_t qir = (size_t)(i0s + l31) * CQK;
        bf16x8 aih0 = *(const bf16x8*)(qhi + qir + 8 * h);
        bf16x8 aih1 = *(const bf16x8*)(qhi + qir + 16 + 8 * h);
        bf16x8 ail0 = *(const bf16x8*)(qlo + qir + 8 * h);
        bf16x8 ail1 = *(const bf16x8*)(qlo + qir + 16 + 8 * h);

        // bias for rows i = i0s + 4h + r + 8rg
        f32x4 b4[4];
#pragma unroll
        for (int rg = 0; rg < 4; ++rg)
            b4[rg] = *(const f32x4*)(bias + i0s + 8 * rg + 4 * h);

        // E tile: D[row=i][col=j], lane: col j=l31, rows i=4h+r+8rg
        f32x16 ee = {0,0,0,0,0,0,0,0,0,0,0,0,0,0,0,0};
        ee = __builtin_amdgcn_mfma_f32_32x32x16_bf16(ail0, bjh0, ee, 0, 0, 0);
        ee = __builtin_amdgcn_mfma_f32_32x32x16_bf16(ail1, bjh1, ee, 0, 0, 0);
        ee = __builtin_amdgcn_mfma_f32_32x32x16_bf16(aih0, bjl0, ee, 0, 0, 0);
        ee = __builtin_amdgcn_mfma_f32_32x32x16_bf16(aih1, bjl1, ee, 0, 0, 0);
        ee = __builtin_amdgcn_mfma_f32_32x32x16_bf16(aih0, bjh0, ee, 0, 0, 0);
        ee = __builtin_amdgcn_mfma_f32_32x32x16_bf16(aih1, bjh1, ee, 0, 0, 0);

        // p = exp2(e - bias_i), pack pairs (i even, i odd) -> dwords
        int d0[4], d1[4];
#pragma unroll
        for (int rg = 0; rg < 4; ++rg) {
            float p0 = fexp2(ee[4 * rg + 0] - b4[rg][0]);
            float p1 = fexp2(ee[4 * rg + 1] - b4[rg][1]);
            float p2 = fexp2(ee[4 * rg + 2] - b4[rg][2]);
            float p3 = fexp2(ee[4 * rg + 3] - b4[rg][3]);
            d0[rg] = packbf(p0, p1);
            d1[rg] = packbf(p2, p3);
        }

        // redistribute to PV A-frag layout: lane (j=l31, h) k=i 8h..8h+7
#pragma unroll
        for (int s2 = 0; s2 < 2; ++s2) {
            const int a  = d0[2 * s2], b = d0[2 * s2 + 1];
            const int c  = d1[2 * s2], d = d1[2 * s2 + 1];
            const int pa = __shfl_xor(a, 32);
            const int pb = __shfl_xor(b, 32);
            const int pc = __shfl_xor(c, 32);
            const int pd = __shfl_xor(d, 32);
            union { int i[4]; bf16x8 v; } pf;
            pf.i[0] = h ? pb : a;    // k-pair (0,1) / (8,9)
            pf.i[1] = h ? pd : c;    // k-pair (2,3) / (10,11)
            pf.i[2] = h ? b : pa;    // k-pair (4,5) / (12,13)
            pf.i[3] = h ? d : pc;    // k-pair (6,7) / (14,15)
#pragma unroll
            for (int cf = 0; cf < 4; ++cf)
                acc[cf] = __builtin_amdgcn_mfma_f32_32x32x16_bf16(
                    pf.v, vf[s2][cf], acc[cf], 0, 0, 0);
        }
    }

    if (DIRECT) {
        const float g = gp[0];
#pragma unroll
        for (int cf = 0; cf < 4; ++cf) {
            const int c = cb + 32 * cf + l31;
#pragma unroll
            for (int rg = 0; rg < 4; ++rg)
#pragma unroll
                for (int r = 0; r < 4; ++r) {
                    const int j = jrow + 4 * h + r + 8 * rg;
                    dst[(size_t)j * CC + c] =
                        fmaf(g, acc[cf][4 * rg + r], f[(size_t)j * CC + c]);
                }
        }
    } else {
        float* part = dst + (size_t)isp * NN * CC;
#pragma unroll
        for (int cf = 0; cf < 4; ++cf) {
            const int c = cb + 32 * cf + l31;
#pragma unroll
            for (int rg = 0; rg < 4; ++rg)
#pragma unroll
                for (int r = 0; r < 4; ++r) {
                    const int j = jrow + 4 * h + r + 8 * rg;
                    part[(size_t)j * CC + c] = acc[cf][4 * rg + r];
                }
        }
    }
}

// ---------------------------------------------------------------------------
// Kernel 4: out = gamma * sum_splits(part) + f
// ---------------------------------------------------------------------------
template<int SPLIT>
__global__ __launch_bounds__(256) void reduce_kernel(
    const float* __restrict__ part, const float* __restrict__ f,
    const float* __restrict__ gp, float* __restrict__ out)
{
    size_t idx = (size_t)blockIdx.x * 256 + threadIdx.x;   // f32x4 units
    const f32x4* p4 = (const f32x4*)part;
    f32x4 s = p4[idx];
#pragma unroll
    for (int k = 1; k < SPLIT; ++k) s += p4[(size_t)k * (NN * CC / 4) + idx];
    f32x4 fv = ((const f32x4*)f)[idx];
    float g = gp[0];
    f32x4 o;
#pragma unroll
    for (int r = 0; r < 4; ++r) o[r] = fmaf(g, s[r], fv[r]);
    ((f32x4*)out)[idx] = o;
}

// ---------------------------------------------------------------------------
extern "C" void kernel_launch(void* const* d_in, const int* in_sizes, int n_in,
                              void* d_out, int out_size, void* d_ws, size_t ws_size,
                              hipStream_t stream) {
    const float* f     = (const float*)d_in[0];
    const float* Wqk   = (const float*)d_in[1];
    const float* Wv    = (const float*)d_in[2];
    const float* bv    = (const float*)d_in[3];
    const float* gamma = (const float*)d_in[4];
    float* out = (float*)d_out;

    char* ws = (char*)d_ws;
    unsigned short* qhi = (unsigned short*)ws;                         // 512 KB
    unsigned short* qlo = (unsigned short*)(ws + (512 << 10));         // 512 KB
    unsigned short* vB  = (unsigned short*)(ws + (1 << 20));           // 4 MB
    float* pm   = (float*)(ws + (5 << 20));                            // 64 KB
    float* ps   = (float*)(ws + (5 << 20) + (64 << 10));               // 64 KB
    float* bias = (float*)(ws + (5 << 20) + (128 << 10));              // 32 KB
    float* part = (float*)(ws + (6 << 20));                            // ISPLIT*8 MB

    proj_q_kernel<<<dim3(NN / 8), dim3(256), 0, stream>>>(f, Wqk, qhi, qlo);
    proj_v_kernel<<<dim3(NN / 32), dim3(256), 0, stream>>>(f, Wv, bv, vB);
    pass1_kernel<<<dim3((NN / 32) * JS), dim3(256), 0, stream>>>(qhi, qlo, pm, ps);
    finalize_kernel<<<dim3(NN / 256), dim3(256), 0, stream>>>(pm, ps, bias);

    const size_t PB = (size_t)NN * CC * 4;   // one partial buffer: 8 MB
    const size_t B0 = (size_t)6 << 20;
    if (ws_size >= B0 + 4 * PB) {
        pass2_kernel<4, false><<<dim3(64 * 4), dim3(512), 0, stream>>>(qhi, qlo, vB, bias, f, gamma, part);
        reduce_kernel<4><<<dim3(NN * CC / 1024), dim3(256), 0, stream>>>(part, f, gamma, out);
    } else if (ws_size >= B0 + 2 * PB) {
        pass2_kernel<2, false><<<dim3(64 * 2), dim3(512), 0, stream>>>(qhi, qlo, vB, bias, f, gamma, part);
        reduce_kernel<2><<<dim3(NN * CC / 1024), dim3(256), 0, stream>>>(part, f, gamma, out);
    } else if (ws_size >= B0 + 1 * PB) {
        pass2_kernel<1, false><<<dim3(64), dim3(512), 0, stream>>>(qhi, qlo, vB, bias, f, gamma, part);
        reduce_kernel<1><<<dim3(NN * CC / 1024), dim3(256), 0, stream>>>(part, f, gamma, out);
    } else {
        pass2_kernel<1, true><<<dim3(64), dim3(512), 0, stream>>>(qhi, qlo, vB, bias, f, gamma, out);
    }
}

// Round 5
// 162.845 us; speedup vs baseline: 1.5239x; 1.2153x over previous
//
#include <hip/hip_runtime.h>
#include <hip/hip_bf16.h>

#define NN 8192
#define CC 256
#define CQK 32
#define JS 4   // pass1 j-splits

using bf16x8 = __attribute__((ext_vector_type(8))) short;
using s16x4  = __attribute__((ext_vector_type(4))) short;
using f32x4  = __attribute__((ext_vector_type(4))) float;
using f32x16 = __attribute__((ext_vector_type(16))) float;

static __device__ __forceinline__ unsigned short f2bf(float x) {
    union { __hip_bfloat16 h; unsigned short u; } cv;
    cv.h = __float2bfloat16(x);
    return cv.u;
}
static __device__ __forceinline__ float bf2f(unsigned short u) {
    union { unsigned short u; __hip_bfloat16 h; } cv;
    cv.u = u;
    return __bfloat162float(cv.h);
}
static __device__ __forceinline__ float fexp2(float x) { return __builtin_amdgcn_exp2f(x); }
static __device__ __forceinline__ int packbf(float lo, float hi) {
    return (int)f2bf(lo) | ((int)f2bf(hi) << 16);
}

// ---------------------------------------------------------------------------
// Kernel 1a: q = (f @ Wqk^T) * sqrt(log2 e), stored hi/lo bf16.
// ---------------------------------------------------------------------------
__global__ __launch_bounds__(256) void proj_q_kernel(
    const float* __restrict__ f, const float* __restrict__ Wqk,
    unsigned short* __restrict__ qhi, unsigned short* __restrict__ qlo)
{
    __shared__ __align__(16) float fl[8][CC];
    const int t  = threadIdx.x;
    const int r0 = blockIdx.x * 8;
    {
        const float4* src = (const float4*)(f + (size_t)r0 * CC);
        float4* dst = (float4*)&fl[0][0];
        dst[t]       = src[t];
        dst[t + 256] = src[t + 256];
    }
    __syncthreads();
    const int cq = t & 31;
    const int rg = t >> 5;
    const float4* w4 = (const float4*)(Wqk + (size_t)cq * CC);
    float a = 0.f;
    for (int k4 = 0; k4 < 64; ++k4) {
        float4 wq = w4[k4];
        const float4 fv = *(const float4*)&fl[rg][k4 * 4];
        a = fmaf(wq.x, fv.x, a);
        a = fmaf(wq.y, fv.y, a);
        a = fmaf(wq.z, fv.z, a);
        a = fmaf(wq.w, fv.w, a);
    }
    a *= 1.2011224087864498f;              // sqrt(log2 e) -> exp2 domain
    unsigned short hh = f2bf(a);
    unsigned short ll = f2bf(a - bf2f(hh));
    qhi[(size_t)(r0 + rg) * CQK + cq] = hh;
    qlo[(size_t)(r0 + rg) * CQK + cq] = ll;
}

// ---------------------------------------------------------------------------
// Kernel 1b: v = f @ Wv^T + bv via bf16 32x32x16 MFMA.
// Output layout vB[i>>3][c][i&7] bf16 -> PV B-frags are coalesced b128 loads.
// ---------------------------------------------------------------------------
__global__ __launch_bounds__(256, 4) void proj_v_kernel(
    const float* __restrict__ f, const float* __restrict__ Wv,
    const float* __restrict__ bv, unsigned short* __restrict__ vB)
{
    const int t    = threadIdx.x;
    const int lane = t & 63;
    const int w    = t >> 6;
    const int l31  = lane & 31;
    const int h    = lane >> 5;
    const int nb   = blockIdx.x * 32;
    const int cb   = w * 64;

    f32x16 acc[2];
#pragma unroll
    for (int cf = 0; cf < 2; ++cf)
#pragma unroll
        for (int r = 0; r < 16; ++r) acc[cf][r] = 0.f;

    const float* frow = f + (size_t)(nb + l31) * CC;
#pragma unroll
    for (int ks = 0; ks < 16; ++ks) {
        const int k0 = ks * 16 + 8 * h;
        float4 a0 = *(const float4*)(frow + k0);
        float4 a1 = *(const float4*)(frow + k0 + 4);
        bf16x8 af;
        af[0] = (short)f2bf(a0.x); af[1] = (short)f2bf(a0.y);
        af[2] = (short)f2bf(a0.z); af[3] = (short)f2bf(a0.w);
        af[4] = (short)f2bf(a1.x); af[5] = (short)f2bf(a1.y);
        af[6] = (short)f2bf(a1.z); af[7] = (short)f2bf(a1.w);
#pragma unroll
        for (int cf = 0; cf < 2; ++cf) {
            const float* wrow = Wv + (size_t)(cb + 32 * cf + l31) * CC + k0;
            float4 b0 = *(const float4*)(wrow);
            float4 b1 = *(const float4*)(wrow + 4);
            bf16x8 bw;
            bw[0] = (short)f2bf(b0.x); bw[1] = (short)f2bf(b0.y);
            bw[2] = (short)f2bf(b0.z); bw[3] = (short)f2bf(b0.w);
            bw[4] = (short)f2bf(b1.x); bw[5] = (short)f2bf(b1.y);
            bw[6] = (short)f2bf(b1.z); bw[7] = (short)f2bf(b1.w);
            acc[cf] = __builtin_amdgcn_mfma_f32_32x32x16_bf16(af, bw, acc[cf], 0, 0, 0);
        }
    }
#pragma unroll
    for (int cf = 0; cf < 2; ++cf) {
        const int cg = cb + 32 * cf + l31;
        const float bvc = bv[cg];
#pragma unroll
        for (int rg = 0; rg < 4; ++rg) {
            const int ib = (nb >> 3) + rg;
            s16x4 pk;
#pragma unroll
            for (int r = 0; r < 4; ++r)
                pk[r] = (short)f2bf(acc[cf][4 * rg + r] + bvc);
            *(s16x4*)(vB + ((size_t)ib * CC + cg) * 8 + 4 * h) = pk;
        }
    }
}

// ---------------------------------------------------------------------------
// Kernel 2: per-i partial softmax stats, 32x32 E tiles, prefetched j-frags,
// split E chains. grid (NN/32)*JS x 256 thr (4 waves, each 1/(4*JS) of j).
// ---------------------------------------------------------------------------
#define P1BODY(C0, C1, C2, C3, N0, N1, N2, N3, NJ)                             \
    {                                                                          \
        const size_t qnr = (size_t)((NJ) + l31) * CQK;                         \
        N0 = *(const bf16x8*)(qhi + qnr + 8 * h);                              \
        N1 = *(const bf16x8*)(qhi + qnr + 16 + 8 * h);                         \
        N2 = *(const bf16x8*)(qlo + qnr + 8 * h);                              \
        N3 = *(const bf16x8*)(qlo + qnr + 16 + 8 * h);                         \
        f32x16 e0 = {0,0,0,0,0,0,0,0,0,0,0,0,0,0,0,0};                         \
        f32x16 e1 = {0,0,0,0,0,0,0,0,0,0,0,0,0,0,0,0};                         \
        e0 = __builtin_amdgcn_mfma_f32_32x32x16_bf16(C2, bih0, e0, 0, 0, 0);   \
        e1 = __builtin_amdgcn_mfma_f32_32x32x16_bf16(C3, bih1, e1, 0, 0, 0);   \
        e0 = __builtin_amdgcn_mfma_f32_32x32x16_bf16(C0, bil0, e0, 0, 0, 0);   \
        e1 = __builtin_amdgcn_mfma_f32_32x32x16_bf16(C1, bil1, e1, 0, 0, 0);   \
        e0 = __builtin_amdgcn_mfma_f32_32x32x16_bf16(C0, bih0, e0, 0, 0, 0);   \
        e1 = __builtin_amdgcn_mfma_f32_32x32x16_bf16(C1, bih1, e1, 0, 0, 0);   \
        f32x16 ee = e0 + e1;                                                   \
        float tm = ee[0];                                                      \
        _Pragma("unroll")                                                      \
        for (int r = 1; r < 16; ++r) tm = fmaxf(tm, ee[r]);                    \
        float mn = fmaxf(m, tm);                                               \
        float a_ = 0.f;                                                        \
        _Pragma("unroll")                                                      \
        for (int r = 0; r < 16; ++r) a_ += fexp2(ee[r] - mn);                  \
        s = fmaf(s, fexp2(m - mn), a_);                                        \
        m = mn;                                                                \
    }

__global__ __launch_bounds__(256, 2) void pass1_kernel(
    const unsigned short* __restrict__ qhi,
    const unsigned short* __restrict__ qlo,
    float* __restrict__ pm, float* __restrict__ ps)
{
    const int t    = threadIdx.x;
    const int lane = t & 63;
    const int w    = t >> 6;
    const int l31  = lane & 31;
    const int h    = lane >> 5;
    const int i0   = (blockIdx.x & 255) * 32;
    const int js   = blockIdx.x >> 8;
    const int JCH  = NN / JS / 4;            // 512 j per wave
    const int jbase = js * (NN / JS) + w * JCH;

    const size_t qir = (size_t)(i0 + l31) * CQK;
    const bf16x8 bih0 = *(const bf16x8*)(qhi + qir + 8 * h);
    const bf16x8 bih1 = *(const bf16x8*)(qhi + qir + 16 + 8 * h);
    const bf16x8 bil0 = *(const bf16x8*)(qlo + qir + 8 * h);
    const bf16x8 bil1 = *(const bf16x8*)(qlo + qir + 16 + 8 * h);

    float m = -INFINITY, s = 0.f;

    bf16x8 qa0, qa1, qa2, qa3, qb0, qb1, qb2, qb3;
    {
        const size_t q0 = (size_t)(jbase + l31) * CQK;
        qa0 = *(const bf16x8*)(qhi + q0 + 8 * h);
        qa1 = *(const bf16x8*)(qhi + q0 + 16 + 8 * h);
        qa2 = *(const bf16x8*)(qlo + q0 + 8 * h);
        qa3 = *(const bf16x8*)(qlo + q0 + 16 + 8 * h);
    }
    for (int st = 0; st < JCH; st += 64) {
        P1BODY(qa0, qa1, qa2, qa3, qb0, qb1, qb2, qb3, jbase + st + 32)
        const int nx = (st + 64 < JCH) ? jbase + st + 64 : jbase + st;
        P1BODY(qb0, qb1, qb2, qb3, qa0, qa1, qa2, qa3, nx)
    }
    {   // merge the two h-halves (same i-col)
        float mo = __shfl_xor(m, 32);
        float so = __shfl_xor(s, 32);
        float mn = fmaxf(m, mo);
        s = s * fexp2(m - mn) + so * fexp2(mo - mn);
        m = mn;
    }
    __shared__ float rm[4][32];
    __shared__ float rs[4][32];
    if (lane < 32) { rm[w][l31] = m; rs[w][l31] = s; }
    __syncthreads();
    if (t < 32) {
        float mf = rm[0][t], sf = rs[0][t];
#pragma unroll
        for (int ww = 1; ww < 4; ++ww) {
            float m2 = rm[ww][t], s2 = rs[ww][t];
            float mn = fmaxf(mf, m2);
            sf = sf * fexp2(mf - mn) + s2 * fexp2(m2 - mn);
            mf = mn;
        }
        pm[(size_t)js * NN + i0 + t] = mf;
        ps[(size_t)js * NN + i0 + t] = sf;
    }
}

// ---------------------------------------------------------------------------
// Kernel 2b: merge j-split partials; bias[i] = m_i + log2(s_i).
// ---------------------------------------------------------------------------
__global__ __launch_bounds__(256) void finalize_kernel(
    const float* __restrict__ pm, const float* __restrict__ ps,
    float* __restrict__ bias)
{
    int i = blockIdx.x * 256 + threadIdx.x;
    float m = pm[i], s = ps[i];
#pragma unroll
    for (int k = 1; k < JS; ++k) {
        float m2 = pm[(size_t)k * NN + i], s2 = ps[(size_t)k * NN + i];
        float mn = fmaxf(m, m2);
        s = s * fexp2(m - mn) + s2 * fexp2(m2 - mn);
        m = mn;
    }
    bias[i] = m + __builtin_amdgcn_logf(s);   // v_log_f32 = log2
}

// ---------------------------------------------------------------------------
// Kernel 3: barrier-free PV with q-prefetch + split E chains.
// grid: ISPLIT-dep x 256 thr (4 waves). Block: 64 j x 256 c. Wave: 32j x 128c.
// P redistribution: round-3-verified shfl_xor(32)+select (E regs lane j=l31,
// i=4h+r+8rg -> PV A-frag lane j=l31, k=i in 8h..8h+7).
// ---------------------------------------------------------------------------
#define P2BODY(I, C0, C1, C2, C3, N0, N1, N2, N3, NI)                          \
    {                                                                          \
        const size_t qnr = (size_t)((NI) + l31) * CQK;                         \
        N0 = *(const bf16x8*)(qhi + qnr + 8 * h);                              \
        N1 = *(const bf16x8*)(qhi + qnr + 16 + 8 * h);                         \
        N2 = *(const bf16x8*)(qlo + qnr + 8 * h);                              \
        N3 = *(const bf16x8*)(qlo + qnr + 16 + 8 * h);                         \
        bf16x8 vf[2][4];                                                       \
        _Pragma("unroll")                                                      \
        for (int s2 = 0; s2 < 2; ++s2)                                         \
            _Pragma("unroll")                                                  \
            for (int cf = 0; cf < 4; ++cf)                                     \
                vf[s2][cf] = *(const bf16x8*)(                                 \
                    vB + ((size_t)(((I) >> 3) + 2 * s2 + h) * CC + cb + 32 * cf + l31) * 8); \
        f32x4 b4[4];                                                           \
        _Pragma("unroll")                                                      \
        for (int rg = 0; rg < 4; ++rg)                                         \
            b4[rg] = *(const f32x4*)(bias + (I) + 8 * rg + 4 * h);             \
        f32x16 e0 = {0,0,0,0,0,0,0,0,0,0,0,0,0,0,0,0};                         \
        f32x16 e1 = {0,0,0,0,0,0,0,0,0,0,0,0,0,0,0,0};                         \
        e0 = __builtin_amdgcn_mfma_f32_32x32x16_bf16(C2, bjh0, e0, 0, 0, 0);   \
        e1 = __builtin_amdgcn_mfma_f32_32x32x16_bf16(C3, bjh1, e1, 0, 0, 0);   \
        e0 = __builtin_amdgcn_mfma_f32_32x32x16_bf16(C0, bjl0, e0, 0, 0, 0);   \
        e1 = __builtin_amdgcn_mfma_f32_32x32x16_bf16(C1, bjl1, e1, 0, 0, 0);   \
        e0 = __builtin_amdgcn_mfma_f32_32x32x16_bf16(C0, bjh0, e0, 0, 0, 0);   \
        e1 = __builtin_amdgcn_mfma_f32_32x32x16_bf16(C1, bjh1, e1, 0, 0, 0);   \
        f32x16 ee = e0 + e1;                                                   \
        int d0[4], d1[4];                                                      \
        _Pragma("unroll")                                                      \
        for (int rg = 0; rg < 4; ++rg) {                                       \
            float p0 = fexp2(ee[4 * rg + 0] - b4[rg][0]);                      \
            float p1 = fexp2(ee[4 * rg + 1] - b4[rg][1]);                      \
            float p2 = fexp2(ee[4 * rg + 2] - b4[rg][2]);                      \
            float p3 = fexp2(ee[4 * rg + 3] - b4[rg][3]);                      \
            d0[rg] = packbf(p0, p1);                                           \
            d1[rg] = packbf(p2, p3);                                           \
        }                                                                      \
        _Pragma("unroll")                                                      \
        for (int s2 = 0; s2 < 2; ++s2) {                                       \
            const int a_ = d0[2 * s2], b_ = d0[2 * s2 + 1];                    \
            const int c_ = d1[2 * s2], d_ = d1[2 * s2 + 1];                    \
            const int pa = __shfl_xor(a_, 32);                                 \
            const int pb = __shfl_xor(b_, 32);                                 \
            const int pc = __shfl_xor(c_, 32);                                 \
            const int pd = __shfl_xor(d_, 32);                                 \
            union { int i[4]; bf16x8 v; } pf;                                  \
            pf.i[0] = h ? pb : a_;                                             \
            pf.i[1] = h ? pd : c_;                                             \
            pf.i[2] = h ? b_ : pa;                                             \
            pf.i[3] = h ? d_ : pc;                                             \
            _Pragma("unroll")                                                  \
            for (int cf = 0; cf < 4; ++cf)                                     \
                acc[cf] = __builtin_amdgcn_mfma_f32_32x32x16_bf16(             \
                    pf.v, vf[s2][cf], acc[cf], 0, 0, 0);                       \
        }                                                                      \
    }

template<int ISPLIT, bool DIRECT>
__global__ __launch_bounds__(256, 2) void pass2_kernel(
    const unsigned short* __restrict__ qhi,
    const unsigned short* __restrict__ qlo,
    const unsigned short* __restrict__ vB,
    const float* __restrict__ bias,
    const float* __restrict__ f,
    const float* __restrict__ gp,
    float* __restrict__ dst)
{
    const int t    = threadIdx.x;
    const int lane = t & 63;
    const int w    = t >> 6;
    const int l31  = lane & 31;
    const int h    = lane >> 5;

    int jblk, isp;
    if (ISPLIT == 4) {
        // XCD-aware: each XCD pair owns one isp -> its vB slice stays in L2
        const int bid = blockIdx.x;
        isp  = (bid & 7) >> 1;
        jblk = ((bid >> 3) << 1) | (bid & 1);   // 0..127, bijective
    } else if (ISPLIT == 2) {
        isp  = blockIdx.x & 1;
        jblk = blockIdx.x >> 1;
    } else {
        isp  = 0;
        jblk = blockIdx.x;
    }
    const int jb   = jblk * 64;
    const int jw   = w & 1, cw = w >> 1;
    const int jrow = jb + 32 * jw;
    const int cb   = 128 * cw;
    const int IL   = NN / ISPLIT;
    const int ibase = isp * IL;
    const int iend  = ibase + IL;

    const size_t qjr = (size_t)(jrow + l31) * CQK;
    const bf16x8 bjh0 = *(const bf16x8*)(qhi + qjr + 8 * h);
    const bf16x8 bjh1 = *(const bf16x8*)(qhi + qjr + 16 + 8 * h);
    const bf16x8 bjl0 = *(const bf16x8*)(qlo + qjr + 8 * h);
    const bf16x8 bjl1 = *(const bf16x8*)(qlo + qjr + 16 + 8 * h);

    f32x16 acc[4];
#pragma unroll
    for (int cf = 0; cf < 4; ++cf)
#pragma unroll
        for (int r = 0; r < 16; ++r) acc[cf][r] = 0.f;

    bf16x8 qa0, qa1, qa2, qa3, qb0, qb1, qb2, qb3;
    {
        const size_t q0 = (size_t)(ibase + l31) * CQK;
        qa0 = *(const bf16x8*)(qhi + q0 + 8 * h);
        qa1 = *(const bf16x8*)(qhi + q0 + 16 + 8 * h);
        qa2 = *(const bf16x8*)(qlo + q0 + 8 * h);
        qa3 = *(const bf16x8*)(qlo + q0 + 16 + 8 * h);
    }
    for (int i0s = ibase; i0s < iend; i0s += 64) {
        P2BODY(i0s,      qa0, qa1, qa2, qa3, qb0, qb1, qb2, qb3, i0s + 32)
        const int nx = (i0s + 64 < iend) ? i0s + 64 : i0s;
        P2BODY(i0s + 32, qb0, qb1, qb2, qb3, qa0, qa1, qa2, qa3, nx)
    }

    if (DIRECT) {
        const float g = gp[0];
#pragma unroll
        for (int cf = 0; cf < 4; ++cf) {
            const int c = cb + 32 * cf + l31;
#pragma unroll
            for (int rg = 0; rg < 4; ++rg)
#pragma unroll
                for (int r = 0; r < 4; ++r) {
                    const int j = jrow + 4 * h + r + 8 * rg;
                    dst[(size_t)j * CC + c] =
                        fmaf(g, acc[cf][4 * rg + r], f[(size_t)j * CC + c]);
                }
        }
    } else {
        float* part = dst + (size_t)isp * NN * CC;
#pragma unroll
        for (int cf = 0; cf < 4; ++cf) {
            const int c = cb + 32 * cf + l31;
#pragma unroll
            for (int rg = 0; rg < 4; ++rg)
#pragma unroll
                for (int r = 0; r < 4; ++r) {
                    const int j = jrow + 4 * h + r + 8 * rg;
                    part[(size_t)j * CC + c] = acc[cf][4 * rg + r];
                }
        }
    }
}

// ---------------------------------------------------------------------------
// Kernel 4: out = gamma * sum_splits(part) + f
// ---------------------------------------------------------------------------
template<int SPLIT>
__global__ __launch_bounds__(256) void reduce_kernel(
    const float* __restrict__ part, const float* __restrict__ f,
    const float* __restrict__ gp, float* __restrict__ out)
{
    size_t idx = (size_t)blockIdx.x * 256 + threadIdx.x;   // f32x4 units
    const f32x4* p4 = (const f32x4*)part;
    f32x4 s = p4[idx];
#pragma unroll
    for (int k = 1; k < SPLIT; ++k) s += p4[(size_t)k * (NN * CC / 4) + idx];
    f32x4 fv = ((const f32x4*)f)[idx];
    float g = gp[0];
    f32x4 o;
#pragma unroll
    for (int r = 0; r < 4; ++r) o[r] = fmaf(g, s[r], fv[r]);
    ((f32x4*)out)[idx] = o;
}

// ---------------------------------------------------------------------------
extern "C" void kernel_launch(void* const* d_in, const int* in_sizes, int n_in,
                              void* d_out, int out_size, void* d_ws, size_t ws_size,
                              hipStream_t stream) {
    const float* f     = (const float*)d_in[0];
    const float* Wqk   = (const float*)d_in[1];
    const float* Wv    = (const float*)d_in[2];
    const float* bv    = (const float*)d_in[3];
    const float* gamma = (const float*)d_in[4];
    float* out = (float*)d_out;

    char* ws = (char*)d_ws;
    unsigned short* qhi = (unsigned short*)ws;                         // 512 KB
    unsigned short* qlo = (unsigned short*)(ws + (512 << 10));         // 512 KB
    unsigned short* vB  = (unsigned short*)(ws + (1 << 20));           // 4 MB
    float* pm   = (float*)(ws + (5 << 20));                            // 128 KB
    float* ps   = (float*)(ws + (5 << 20) + (128 << 10));              // 128 KB
    float* bias = (float*)(ws + (5 << 20) + (256 << 10));              // 32 KB
    float* part = (float*)(ws + (6 << 20));                            // ISPLIT*8 MB

    proj_q_kernel<<<dim3(NN / 8), dim3(256), 0, stream>>>(f, Wqk, qhi, qlo);
    proj_v_kernel<<<dim3(NN / 32), dim3(256), 0, stream>>>(f, Wv, bv, vB);
    pass1_kernel<<<dim3((NN / 32) * JS), dim3(256), 0, stream>>>(qhi, qlo, pm, ps);
    finalize_kernel<<<dim3(NN / 256), dim3(256), 0, stream>>>(pm, ps, bias);

    const size_t PB = (size_t)NN * CC * 4;   // one partial buffer: 8 MB
    const size_t B0 = (size_t)6 << 20;
    if (ws_size >= B0 + 4 * PB) {
        pass2_kernel<4, false><<<dim3(128 * 4), dim3(256), 0, stream>>>(qhi, qlo, vB, bias, f, gamma, part);
        reduce_kernel<4><<<dim3(NN * CC / 1024), dim3(256), 0, stream>>>(part, f, gamma, out);
    } else if (ws_size >= B0 + 2 * PB) {
        pass2_kernel<2, false><<<dim3(128 * 2), dim3(256), 0, stream>>>(qhi, qlo, vB, bias, f, gamma, part);
        reduce_kernel<2><<<dim3(NN * CC / 1024), dim3(256), 0, stream>>>(part, f, gamma, out);
    } else if (ws_size >= B0 + 1 * PB) {
        pass2_kernel<1, false><<<dim3(128), dim3(256), 0, stream>>>(qhi, qlo, vB, bias, f, gamma, part);
        reduce_kernel<1><<<dim3(NN * CC / 1024), dim3(256), 0, stream>>>(part, f, gamma, out);
    } else {
        pass2_kernel<1, true><<<dim3(128), dim3(256), 0, stream>>>(qhi, qlo, vB, bias, f, gamma, out);
    }
}